// Round 13
// baseline (189.819 us; speedup 1.0000x reference)
//
#include <hip/hip_runtime.h>

#define H 8
#define DH 64
#define NQ 1024
#define NK 2048
#define DIN 512
#define B 4
#define KSPLIT 2
#define KRANGE (NK / KSPLIT)   // 1024
#define KTILES2 (KRANGE / 128) // 8 double-depth tiles
#define BHNQ (B * H * NQ)

typedef __bf16 bf16;
typedef __bf16 bf16x8 __attribute__((ext_vector_type(8)));
typedef __bf16 bf16x4 __attribute__((ext_vector_type(4)));
typedef float floatx4 __attribute__((ext_vector_type(4)));

__device__ inline void gload16(const void* g, void* l) {
  __builtin_amdgcn_global_load_lds(
      (const __attribute__((address_space(1))) void*)g,
      (__attribute__((address_space(3))) void*)l, 16, 0, 0);
}

__device__ inline float fexp2(float x) {
#if __has_builtin(__builtin_amdgcn_exp2f)
  return __builtin_amdgcn_exp2f(x);
#else
  return exp2f(x);
#endif
}

// ---------------- fused Q/KV projection GEMM ---------------------------------
// R13: cvt_w kernel eliminated — weights are read DIRECTLY from fp32 and
// converted during B-staging (float4 loads + casts + ds_write_b128), the
// same convert-in-staging pattern proven for A in R11. Weights are 3 MB
// fp32 total -> fully L2/L3-resident, re-reads never touch HBM.
// Structure otherwise R11: K and V merged (z=1), shared A-tile; Q = z0.
__global__ __launch_bounds__(256) void gemm_qkv(
    const float* __restrict__ xf, const float* __restrict__ cf,
    const float* __restrict__ wqf, const float* __restrict__ wkf, const float* __restrict__ wvf,
    bf16* __restrict__ qb, bf16* __restrict__ kb, bf16* __restrict__ vtb) {
  const bool qmode = (blockIdx.z == 0);
  if (qmode && blockIdx.y >= 64) return;

  __shared__ bf16 Al[2][64 * 32];   // 4 KB each
  __shared__ bf16 Bk[2][128 * 32];  // 8 KB each
  __shared__ bf16 Bv[2][128 * 32];  // 8 KB each (idle in qmode)
  const int t = threadIdx.x;
  const int lane = t & 63, w = t >> 6;
  const int ln = lane & 15, quad = lane >> 4;
  const int wm = (w >> 1) * 32, wn = (w & 1) * 64;
  const int rowBase = blockIdx.y * 64;
  const int colBase = blockIdx.x * 128;

  const float* Af = (qmode ? xf : cf) + (size_t)rowBase * DIN;
  const float* W1 = (qmode ? wqf : wkf) + (size_t)colBase * DIN;
  const float* Wv2 = wvf + (size_t)colBase * DIN;

  floatx4 accK[2][4] = {};
  floatx4 accV[2][4] = {};
  const int rA = t >> 2, oA = (t & 3) * 8;
  const int c0 = t, c1 = t + 256;
  const int rB0 = c0 >> 2, oB0 = (c0 & 3) * 8;
  const int rB1 = c1 >> 2, oB1 = (c1 & 3) * 8;

#define CVT8(PSRC, PDST)                                                       \
  {                                                                            \
    float4 f0_ = *(const float4*)(PSRC);                                       \
    float4 f1_ = *(const float4*)((PSRC) + 4);                                 \
    bf16x8 v_ = {(bf16)f0_.x, (bf16)f0_.y, (bf16)f0_.z, (bf16)f0_.w,           \
                 (bf16)f1_.x, (bf16)f1_.y, (bf16)f1_.z, (bf16)f1_.w};          \
    *(bf16x8*)(PDST) = v_;                                                     \
  }

#define STAGE_ALL(K0V, BUF)                                                    \
  {                                                                            \
    CVT8(Af + (size_t)rA * DIN + (K0V) + oA, &Al[BUF][t * 8]);                 \
    CVT8(W1 + (size_t)rB0 * DIN + (K0V) + oB0, &Bk[BUF][c0 * 8]);              \
    CVT8(W1 + (size_t)rB1 * DIN + (K0V) + oB1, &Bk[BUF][c1 * 8]);              \
    if (!qmode) {                                                              \
      CVT8(Wv2 + (size_t)rB0 * DIN + (K0V) + oB0, &Bv[BUF][c0 * 8]);           \
      CVT8(Wv2 + (size_t)rB1 * DIN + (K0V) + oB1, &Bv[BUF][c1 * 8]);           \
    }                                                                          \
  }

  STAGE_ALL(0, 0);
  __syncthreads();

  for (int k0 = 0; k0 < DIN; k0 += 32) {
    const int cur = (k0 >> 5) & 1, nxt = cur ^ 1;
    if (k0 + 32 < DIN) {
      STAGE_ALL(k0 + 32, nxt);
    }
    bf16x8 af[2], bK[4];
#pragma unroll
    for (int i = 0; i < 2; i++)
      af[i] = *(const bf16x8*)&Al[cur][(wm + i * 16 + ln) * 32 + quad * 8];
#pragma unroll
    for (int j = 0; j < 4; j++)
      bK[j] = *(const bf16x8*)&Bk[cur][(wn + j * 16 + ln) * 32 + quad * 8];
#pragma unroll
    for (int i = 0; i < 2; i++)
#pragma unroll
      for (int j = 0; j < 4; j++)
        accK[i][j] = __builtin_amdgcn_mfma_f32_16x16x32_bf16(af[i], bK[j], accK[i][j], 0, 0, 0);
    if (!qmode) {
      bf16x8 bV[4];
#pragma unroll
      for (int j = 0; j < 4; j++)
        bV[j] = *(const bf16x8*)&Bv[cur][(wn + j * 16 + ln) * 32 + quad * 8];
#pragma unroll
      for (int i = 0; i < 2; i++)
#pragma unroll
        for (int j = 0; j < 4; j++)
          accV[i][j] = __builtin_amdgcn_mfma_f32_16x16x32_bf16(bV[j], af[i], accV[i][j], 0, 0, 0);
    }
    __syncthreads();
  }
#undef STAGE_ALL
#undef CVT8

  if (qmode) {
#pragma unroll
    for (int i = 0; i < 2; i++)
#pragma unroll
      for (int j = 0; j < 4; j++)
#pragma unroll
        for (int r = 0; r < 4; r++) {
          const int m = rowBase + wm + i * 16 + quad * 4 + r;
          const int n = colBase + wn + j * 16 + ln;
          const float v = accK[i][j][r] * 0.125f;
          const int bb = m >> 10, tok = m & 1023;
          const int hh = n >> 6, d = n & 63;
          qb[((((size_t)(bb * H + hh)) << 10) + tok) * DH + d] = (bf16)v;
        }
  } else {
#pragma unroll
    for (int i = 0; i < 2; i++)
#pragma unroll
      for (int j = 0; j < 4; j++)
#pragma unroll
        for (int r = 0; r < 4; r++) {
          const int m = rowBase + wm + i * 16 + quad * 4 + r;
          const int n = colBase + wn + j * 16 + ln;
          const int bb = m >> 11, tok = m & 2047;
          const int hh = n >> 6, d = n & 63;
          kb[((((size_t)(bb * H + hh)) << 11) + tok) * DH + d] = (bf16)accK[i][j][r];
          const int dg = colBase + wn + j * 16 + quad * 4 + r;
          const int mv = rowBase + wm + i * 16 + ln;
          const int bbv = mv >> 11, tokv = mv & 2047;
          const int hhv = dg >> 6, dv = dg & 63;
          vtb[((((size_t)(bbv * H + hhv)) * DH + dv) << 11) + tokv] = (bf16)accV[i][j][r];
        }
  }
}

// ---------------- flash attention, static-max softmax, Nk-split --------------
// R12 structure, FROZEN (best measured, ~51 us): BK=128 (8 tiles, one
// stage+drain+barrier pair per 128 k-rows), swapped-operand QK^T, float4
// bias C-init, raw v_exp, packed-b64 P LDS round-trip, O^T float4 epilogue.
__global__ __launch_bounds__(256) void attn_fwd(
    const bf16* __restrict__ q, const bf16* __restrict__ k,
    const bf16* __restrict__ vt, const float* __restrict__ bias,
    float* __restrict__ op0, float* __restrict__ op1, float* __restrict__ lpart) {
  __shared__ bf16 KL[128 * 64];                             // 16 KB
  __shared__ bf16 VL[64 * 128];                             // 16 KB
  __shared__ __attribute__((aligned(16))) bf16 Pl[4][2][16][64];  // 16 KB
  const int tid = threadIdx.x;
  const int lane = tid & 63, w = tid >> 6;
  const int ln = lane & 15, quad = lane >> 4;
  const int hh = blockIdx.y;
  const int b = blockIdx.z >> 1, ks = blockIdx.z & 1;
  const int q0 = blockIdx.x * 128;
  const int k0 = ks * KRANGE;
  const size_t bh = (size_t)b * H + hh;
  const bf16* qp = q + bh * NQ * DH;
  const bf16* kp = k + bh * NK * DH;
  const bf16* vp = vt + bh * DH * NK;
  // bias: row = q (ln-indexed), k-cols contiguous -> float4 fragments
  const float* bp0 = bias + ((size_t)b * NQ + q0 + w * 32 + ln) * NK + k0 + quad * 4;
  const float* bp1 = bp0 + (size_t)16 * NK;

  bf16x8 qf[2][2];
#pragma unroll
  for (int s = 0; s < 2; s++)
#pragma unroll
    for (int kc = 0; kc < 2; kc++)
      qf[s][kc] = *(const bf16x8*)(qp + (size_t)(q0 + w * 32 + s * 16 + ln) * DH + kc * 32 + quad * 8);

  floatx4 o[2][4] = {};
  floatx4 lac[2] = {};
  const bf16x8 ones = {(bf16)1.f, (bf16)1.f, (bf16)1.f, (bf16)1.f,
                       (bf16)1.f, (bf16)1.f, (bf16)1.f, (bf16)1.f};
  constexpr float L2E = 1.44269504f;
  constexpr float OFF = 34.6246810f;  // 24 * log2(e); scores+bias << 24 always

// one 64-row chunk: QK^T(+bias) -> exp -> P pack via wave-private Pl -> l, PV
#define CHUNK(C, SS)                                                              \
  {                                                                               \
    _Pragma("unroll")                                                             \
    for (int j_ = 0; j_ < 4; j_++)                                                \
      _Pragma("unroll")                                                           \
      for (int kc_ = 0; kc_ < 2; kc_++) {                                         \
        const int kr_ = (C) * 64 + j_ * 16 + ln;                                  \
        bf16x8 kf = *(const bf16x8*)&KL[kr_ * 64 + (((kc_ * 4 + quad) ^ (kr_ & 7)) * 8)]; \
        SS[0][j_] = __builtin_amdgcn_mfma_f32_16x16x32_bf16(kf, qf[0][kc_], SS[0][j_], 0, 0, 0); \
        SS[1][j_] = __builtin_amdgcn_mfma_f32_16x16x32_bf16(kf, qf[1][kc_], SS[1][j_], 0, 0, 0); \
      }                                                                           \
    _Pragma("unroll")                                                             \
    for (int s_ = 0; s_ < 2; s_++)                                                \
      _Pragma("unroll")                                                           \
      for (int j_ = 0; j_ < 4; j_++) {                                            \
        const float e0 = fexp2(fmaf(SS[s_][j_][0], L2E, -OFF));                   \
        const float e1 = fexp2(fmaf(SS[s_][j_][1], L2E, -OFF));                   \
        const float e2 = fexp2(fmaf(SS[s_][j_][2], L2E, -OFF));                   \
        const float e3 = fexp2(fmaf(SS[s_][j_][3], L2E, -OFF));                   \
        bf16x4 pv4 = {(bf16)e0, (bf16)e1, (bf16)e2, (bf16)e3};                    \
        const int tok_ = (j_ * 16 + quad * 4) ^ ((ln & 7) << 3);                  \
        *(bf16x4*)&Pl[w][s_][ln][tok_] = pv4;                                     \
      }                                                                           \
    asm volatile("s_waitcnt lgkmcnt(0)" ::: "memory");                            \
    bf16x8 pt[2][2];                                                              \
    _Pragma("unroll")                                                             \
    for (int s_ = 0; s_ < 2; s_++)                                                \
      _Pragma("unroll")                                                           \
      for (int kc_ = 0; kc_ < 2; kc_++) {                                         \
        const int tok_ = (kc_ * 32 + quad * 8) ^ ((ln & 7) << 3);                 \
        pt[s_][kc_] = *(const bf16x8*)&Pl[w][s_][ln][tok_];                       \
      }                                                                           \
    _Pragma("unroll")                                                             \
    for (int s_ = 0; s_ < 2; s_++)                                                \
      _Pragma("unroll")                                                           \
      for (int kc_ = 0; kc_ < 2; kc_++)                                           \
        lac[s_] = __builtin_amdgcn_mfma_f32_16x16x32_bf16(ones, pt[s_][kc_], lac[s_], 0, 0, 0); \
    _Pragma("unroll")                                                             \
    for (int jn_ = 0; jn_ < 4; jn_++)                                             \
      _Pragma("unroll")                                                           \
      for (int kc_ = 0; kc_ < 2; kc_++) {                                         \
        const int vr_ = jn_ * 16 + ln;                                            \
        bf16x8 vf = *(const bf16x8*)&VL[vr_ * 128 + (((C) * 8 + ((kc_ * 4 + quad) ^ (vr_ & 7))) * 8)]; \
        o[0][jn_] = __builtin_amdgcn_mfma_f32_16x16x32_bf16(vf, pt[0][kc_], o[0][jn_], 0, 0, 0); \
        o[1][jn_] = __builtin_amdgcn_mfma_f32_16x16x32_bf16(vf, pt[1][kc_], o[1][jn_], 0, 0, 0); \
      }                                                                           \
  }

  for (int tt = 0; tt < KTILES2; tt++) {
    const int nk0 = k0 + tt * 128;
    // ---- stage 128-deep K,V via DMA (256 threads x 4 issues each) ----
#pragma unroll
    for (int s = 0; s < 4; s++) {
      const int i = s * 256 + tid;
      const int srk = i >> 3, sck = (i & 7) ^ (srk & 7);        // K: 128 rows x 8 granules
      gload16(kp + (size_t)(nk0 + srk) * DH + sck * 8, &KL[i * 8]);
      const int srv = i >> 4, scv = (i & 15) ^ (srv & 7);       // V^T: 64 rows x 16 granules
      gload16(vp + (size_t)srv * NK + nk0 + scv * 8, &VL[i * 8]);
    }
    // ---- chunk-0 bias (C-init) issues before the barrier (overlaps drain) ----
    floatx4 s4[2][4];
#pragma unroll
    for (int j = 0; j < 4; j++) {
      s4[0][j] = *(const floatx4*)(bp0 + tt * 128 + j * 16);
      s4[1][j] = *(const floatx4*)(bp1 + tt * 128 + j * 16);
    }
    __syncthreads();
    // ---- chunk-1 bias issues here: overlaps chunk-0 compute ----
    floatx4 b1[2][4];
#pragma unroll
    for (int j = 0; j < 4; j++) {
      b1[0][j] = *(const floatx4*)(bp0 + tt * 128 + 64 + j * 16);
      b1[1][j] = *(const floatx4*)(bp1 + tt * 128 + 64 + j * 16);
    }
    CHUNK(0, s4);
    CHUNK(1, b1);
    __syncthreads();
  }
#undef CHUNK

  // ---- epilogue: O^T cols q = ln, rows d = jn*16+quad*4+r -> float4 stores --
#pragma unroll
  for (int s = 0; s < 2; s++) {
    float* op = (ks ? op1 : op0) +
                ((size_t)b * NQ + q0 + w * 32 + s * 16 + ln) * DIN + hh * 64 + quad * 4;
#pragma unroll
    for (int jn = 0; jn < 4; jn++)
      *(floatx4*)(op + jn * 16) = o[s][jn];
    if (quad == 0)
      lpart[((size_t)ks * B * H + b * H + hh) * NQ + q0 + w * 32 + s * 16 + ln] = lac[s][0];
  }
}

// ---------------- final projection fused with K-split combine ----------------
// R7 tiling (32x128, grid (4,128) = 2 blocks/CU) + R13: Wo read directly
// from fp32 and converted during B-staging (cvt kernel eliminated).
__global__ __launch_bounds__(256) void gemm_out(
    const float* __restrict__ op0, const float* __restrict__ op1,
    const float* __restrict__ lp, const float* __restrict__ Wf,
    float* __restrict__ outf, const float* __restrict__ bo) {
  __shared__ bf16 Al[2][32 * 32];   // 2 KB each
  __shared__ bf16 Bl[2][128 * 32];  // 8 KB each
  const int t = threadIdx.x;
  const int lane = t & 63, w = t >> 6;
  const int ln = lane & 15, quad = lane >> 4;
  const int wm = (w >> 1) * 16, wn = (w & 1) * 64;
  const int rowBase = blockIdx.y * 32;
  const int colBase = blockIdx.x * 128;

  floatx4 acc[4] = {};
  const int rA = t >> 2, oA = (t & 3) * 8;   // valid for t < 128 (32 rows x 32 cols)
  const int c0 = t, c1 = t + 256;
  const int rB0 = c0 >> 2, oB0 = (c0 & 3) * 8;
  const int rB1 = c1 >> 2, oB1 = (c1 & 3) * 8;
  const int m0 = rowBase + rA;
  const float* Wb = Wf + (size_t)colBase * DIN;

  float linv0[8];
  if (t < 128) {
#pragma unroll
    for (int h = 0; h < 8; h++) {
      const int i0 = ((m0 >> 10) * H + h) * NQ + (m0 & 1023);
      linv0[h] = 1.0f / (lp[i0] + lp[BHNQ + i0]);
    }
  }

#define CVT8O(PSRC, PDST)                                                      \
  {                                                                            \
    float4 f0_ = *(const float4*)(PSRC);                                       \
    float4 f1_ = *(const float4*)((PSRC) + 4);                                 \
    bf16x8 v_ = {(bf16)f0_.x, (bf16)f0_.y, (bf16)f0_.z, (bf16)f0_.w,           \
                 (bf16)f1_.x, (bf16)f1_.y, (bf16)f1_.z, (bf16)f1_.w};          \
    *(bf16x8*)(PDST) = v_;                                                     \
  }

#define STAGE_AB(K0V, BUF)                                                     \
  {                                                                            \
    if (t < 128) {                                                             \
      const float sA = linv0[(K0V) >> 6];                                      \
      const float* pa0 = op0 + (size_t)m0 * DIN + (K0V) + oA;                  \
      const float* pa1 = op1 + (size_t)m0 * DIN + (K0V) + oA;                  \
      float4 xa = *(const float4*)pa0, xb2 = *(const float4*)(pa0 + 4);        \
      float4 ya = *(const float4*)pa1, yb = *(const float4*)(pa1 + 4);         \
      bf16x8 v0 = {(bf16)((xa.x + ya.x) * sA), (bf16)((xa.y + ya.y) * sA),     \
                   (bf16)((xa.z + ya.z) * sA), (bf16)((xa.w + ya.w) * sA),     \
                   (bf16)((xb2.x + yb.x) * sA), (bf16)((xb2.y + yb.y) * sA),   \
                   (bf16)((xb2.z + yb.z) * sA), (bf16)((xb2.w + yb.w) * sA)};  \
      *(bf16x8*)&Al[BUF][t * 8] = v0;                                          \
    }                                                                          \
    CVT8O(Wb + (size_t)rB0 * DIN + (K0V) + oB0, &Bl[BUF][c0 * 8]);             \
    CVT8O(Wb + (size_t)rB1 * DIN + (K0V) + oB1, &Bl[BUF][c1 * 8]);             \
  }

  STAGE_AB(0, 0);
  __syncthreads();

#pragma unroll
  for (int kk = 0; kk < 16; kk++) {
    const int cur = kk & 1, nxt = cur ^ 1;
    if (kk < 15) {
      STAGE_AB((kk + 1) * 32, nxt);
    }
    bf16x8 af, bfr[4];
    af = *(const bf16x8*)&Al[cur][(wm + ln) * 32 + quad * 8];
#pragma unroll
    for (int j = 0; j < 4; j++)
      bfr[j] = *(const bf16x8*)&Bl[cur][(wn + j * 16 + ln) * 32 + quad * 8];
#pragma unroll
    for (int j = 0; j < 4; j++)
      acc[j] = __builtin_amdgcn_mfma_f32_16x16x32_bf16(af, bfr[j], acc[j], 0, 0, 0);
    __syncthreads();
  }
#undef STAGE_AB
#undef CVT8O

#pragma unroll
  for (int j = 0; j < 4; j++)
#pragma unroll
    for (int r = 0; r < 4; r++) {
      const int m = rowBase + wm + quad * 4 + r;
      const int n = colBase + wn + j * 16 + ln;
      outf[(size_t)m * DIN + n] = acc[j][r] + bo[n];
    }
}

extern "C" void kernel_launch(void* const* d_in, const int* in_sizes, int n_in,
                              void* d_out, int out_size, void* d_ws, size_t ws_size,
                              hipStream_t stream) {
  const float* x    = (const float*)d_in[0];
  const float* ctx  = (const float*)d_in[1];
  const float* bias = (const float*)d_in[2];
  const float* Wq   = (const float*)d_in[3];
  const float* Wk   = (const float*)d_in[4];
  const float* Wv   = (const float*)d_in[5];
  const float* Wo   = (const float*)d_in[6];
  const float* bo   = (const float*)d_in[7];
  float* out = (float*)d_out;

  char* p = (char*)d_ws;
  bf16* qb   = (bf16*)(p + 0);              // 4 MB
  bf16* kb   = (bf16*)(p + 4194304);        // 8 MB
  bf16* vtb  = (bf16*)(p + 12582912);       // 8 MB
  float* op0 = (float*)(p + 20971520);      // 8 MB
  float* op1 = (float*)(p + 29360128);      // 8 MB
  float* lpart = (float*)(p + 37748736);    // 256 KB

  gemm_qkv<<<dim3(4, 128, 2), 256, 0, stream>>>(x, ctx, Wq, Wk, Wv, qb, kb, vtb);
  attn_fwd<<<dim3(NQ / 128, H, B * KSPLIT), 256, 0, stream>>>(qb, kb, vtb, bias, op0, op1, lpart);
  gemm_out<<<dim3(4, 128), 256, 0, stream>>>(op0, op1, lpart, Wo, out, bo);
}

// Round 14
// 184.169 us; speedup vs baseline: 1.0307x; 1.0307x over previous
//
#include <hip/hip_runtime.h>

#define H 8
#define DH 64
#define NQ 1024
#define NK 2048
#define DIN 512
#define B 4
#define KSPLIT 2
#define KRANGE (NK / KSPLIT)   // 1024
#define KTILES2 (KRANGE / 128) // 8 double-depth tiles
#define BHNQ (B * H * NQ)

typedef __bf16 bf16;
typedef __bf16 bf16x8 __attribute__((ext_vector_type(8)));
typedef __bf16 bf16x4 __attribute__((ext_vector_type(4)));
typedef float floatx4 __attribute__((ext_vector_type(4)));

__device__ inline void gload16(const void* g, void* l) {
  __builtin_amdgcn_global_load_lds(
      (const __attribute__((address_space(1))) void*)g,
      (__attribute__((address_space(3))) void*)l, 16, 0, 0);
}

__device__ inline float fexp2(float x) {
#if __has_builtin(__builtin_amdgcn_exp2f)
  return __builtin_amdgcn_exp2f(x);
#else
  return exp2f(x);
#endif
}

// ---------------- fp32 -> bf16 convert, WEIGHTS ONLY (1M floats) -------------
__global__ void cvt_w(const float* __restrict__ wq, const float* __restrict__ wk,
                      const float* __restrict__ wv, const float* __restrict__ wo,
                      bf16* wqb, bf16* wkb, bf16* wvb, bf16* wob) {
  long i = ((long)blockIdx.x * 256 + threadIdx.x) * 4;
  const float* s; bf16* d; long o;
  if (i < 262144)      { s = wq; d = wqb; o = i; }
  else if (i < 524288) { s = wk; d = wkb; o = i - 262144; }
  else if (i < 786432) { s = wv; d = wvb; o = i - 524288; }
  else                 { s = wo; d = wob; o = i - 786432; }
  float4 f = *(const float4*)(s + o);
  bf16x4 v = { (bf16)f.x, (bf16)f.y, (bf16)f.z, (bf16)f.w };
  *(bf16x4*)(d + o) = v;
}

// ---------------- fused Q/KV projection GEMM ---------------------------------
// R11 structure: K and V merged (z=1), shared A-tile; A read directly from
// fp32 x/ctx with convert-in-staging; B tiles DMA'd from bf16 weights
// (R13 showed sync fp32 B-staging regresses: async global_load_lds for the
// large operand is worth more than eliminating cvt_w). Q = z0.
__global__ __launch_bounds__(256) void gemm_qkv(
    const float* __restrict__ xf, const float* __restrict__ cf,
    const bf16* __restrict__ wqb, const bf16* __restrict__ wkb, const bf16* __restrict__ wvb,
    bf16* __restrict__ qb, bf16* __restrict__ kb, bf16* __restrict__ vtb) {
  const bool qmode = (blockIdx.z == 0);
  if (qmode && blockIdx.y >= 64) return;

  __shared__ bf16 Al[2][64 * 32];   // 4 KB each
  __shared__ bf16 Bk[2][128 * 32];  // 8 KB each
  __shared__ bf16 Bv[2][128 * 32];  // 8 KB each (idle in qmode)
  const int t = threadIdx.x;
  const int lane = t & 63, w = t >> 6;
  const int ln = lane & 15, quad = lane >> 4;
  const int wm = (w >> 1) * 32, wn = (w & 1) * 64;
  const int rowBase = blockIdx.y * 64;
  const int colBase = blockIdx.x * 128;

  const float* Af = (qmode ? xf : cf) + (size_t)rowBase * DIN;
  const bf16* W1 = qmode ? wqb : wkb;

  floatx4 accK[2][4] = {};
  floatx4 accV[2][4] = {};
  const int rA = t >> 2, oA = (t & 3) * 8;
  const int c0 = t, c1 = t + 256;
  const int rB0 = c0 >> 2, oB0 = (c0 & 3) * 8;
  const int rB1 = c1 >> 2, oB1 = (c1 & 3) * 8;
  const bf16* Wb1 = W1 + (size_t)colBase * DIN;
  const bf16* Wbv = wvb + (size_t)colBase * DIN;

#define STAGE_AF(K0V, BUF)                                                     \
  {                                                                            \
    const float* pa = Af + (size_t)rA * DIN + (K0V) + oA;                      \
    float4 f0 = *(const float4*)pa;                                            \
    float4 f1 = *(const float4*)(pa + 4);                                      \
    bf16x8 v = {(bf16)f0.x, (bf16)f0.y, (bf16)f0.z, (bf16)f0.w,                \
                (bf16)f1.x, (bf16)f1.y, (bf16)f1.z, (bf16)f1.w};               \
    *(bf16x8*)&Al[BUF][t * 8] = v;                                             \
  }

  STAGE_AF(0, 0);
  gload16(Wb1 + (size_t)rB0 * DIN + oB0, &Bk[0][c0 * 8]);
  gload16(Wb1 + (size_t)rB1 * DIN + oB1, &Bk[0][c1 * 8]);
  if (!qmode) {
    gload16(Wbv + (size_t)rB0 * DIN + oB0, &Bv[0][c0 * 8]);
    gload16(Wbv + (size_t)rB1 * DIN + oB1, &Bv[0][c1 * 8]);
  }
  __syncthreads();

  for (int k0 = 0; k0 < DIN; k0 += 32) {
    const int cur = (k0 >> 5) & 1, nxt = cur ^ 1;
    if (k0 + 32 < DIN) {
      STAGE_AF(k0 + 32, nxt);
      gload16(Wb1 + (size_t)rB0 * DIN + k0 + 32 + oB0, &Bk[nxt][c0 * 8]);
      gload16(Wb1 + (size_t)rB1 * DIN + k0 + 32 + oB1, &Bk[nxt][c1 * 8]);
      if (!qmode) {
        gload16(Wbv + (size_t)rB0 * DIN + k0 + 32 + oB0, &Bv[nxt][c0 * 8]);
        gload16(Wbv + (size_t)rB1 * DIN + k0 + 32 + oB1, &Bv[nxt][c1 * 8]);
      }
    }
    bf16x8 af[2], bK[4];
#pragma unroll
    for (int i = 0; i < 2; i++)
      af[i] = *(const bf16x8*)&Al[cur][(wm + i * 16 + ln) * 32 + quad * 8];
#pragma unroll
    for (int j = 0; j < 4; j++)
      bK[j] = *(const bf16x8*)&Bk[cur][(wn + j * 16 + ln) * 32 + quad * 8];
#pragma unroll
    for (int i = 0; i < 2; i++)
#pragma unroll
      for (int j = 0; j < 4; j++)
        accK[i][j] = __builtin_amdgcn_mfma_f32_16x16x32_bf16(af[i], bK[j], accK[i][j], 0, 0, 0);
    if (!qmode) {
      bf16x8 bV[4];
#pragma unroll
      for (int j = 0; j < 4; j++)
        bV[j] = *(const bf16x8*)&Bv[cur][(wn + j * 16 + ln) * 32 + quad * 8];
#pragma unroll
      for (int i = 0; i < 2; i++)
#pragma unroll
        for (int j = 0; j < 4; j++)
          accV[i][j] = __builtin_amdgcn_mfma_f32_16x16x32_bf16(bV[j], af[i], accV[i][j], 0, 0, 0);
    }
    __syncthreads();
  }
#undef STAGE_AF

  if (qmode) {
#pragma unroll
    for (int i = 0; i < 2; i++)
#pragma unroll
      for (int j = 0; j < 4; j++)
#pragma unroll
        for (int r = 0; r < 4; r++) {
          const int m = rowBase + wm + i * 16 + quad * 4 + r;
          const int n = colBase + wn + j * 16 + ln;
          const float v = accK[i][j][r] * 0.125f;
          const int bb = m >> 10, tok = m & 1023;
          const int hh = n >> 6, d = n & 63;
          qb[((((size_t)(bb * H + hh)) << 10) + tok) * DH + d] = (bf16)v;
        }
  } else {
#pragma unroll
    for (int i = 0; i < 2; i++)
#pragma unroll
      for (int j = 0; j < 4; j++)
#pragma unroll
        for (int r = 0; r < 4; r++) {
          const int m = rowBase + wm + i * 16 + quad * 4 + r;
          const int n = colBase + wn + j * 16 + ln;
          const int bb = m >> 11, tok = m & 2047;
          const int hh = n >> 6, d = n & 63;
          kb[((((size_t)(bb * H + hh)) << 11) + tok) * DH + d] = (bf16)accK[i][j][r];
          const int dg = colBase + wn + j * 16 + quad * 4 + r;
          const int mv = rowBase + wm + i * 16 + ln;
          const int bbv = mv >> 11, tokv = mv & 2047;
          const int hhv = dg >> 6, dv = dg & 63;
          vtb[((((size_t)(bbv * H + hhv)) * DH + dv) << 11) + tokv] = (bf16)accV[i][j][r];
        }
  }
}

// ---------------- flash attention, static-max softmax, Nk-split --------------
// R12 structure, FROZEN (best measured, ~51 us): BK=128 (8 tiles, one
// stage+drain+barrier pair per 128 k-rows), swapped-operand QK^T, float4
// bias C-init, raw v_exp, packed-b64 P LDS round-trip, O^T float4 epilogue.
__global__ __launch_bounds__(256) void attn_fwd(
    const bf16* __restrict__ q, const bf16* __restrict__ k,
    const bf16* __restrict__ vt, const float* __restrict__ bias,
    float* __restrict__ op0, float* __restrict__ op1, float* __restrict__ lpart) {
  __shared__ bf16 KL[128 * 64];                             // 16 KB
  __shared__ bf16 VL[64 * 128];                             // 16 KB
  __shared__ __attribute__((aligned(16))) bf16 Pl[4][2][16][64];  // 16 KB
  const int tid = threadIdx.x;
  const int lane = tid & 63, w = tid >> 6;
  const int ln = lane & 15, quad = lane >> 4;
  const int hh = blockIdx.y;
  const int b = blockIdx.z >> 1, ks = blockIdx.z & 1;
  const int q0 = blockIdx.x * 128;
  const int k0 = ks * KRANGE;
  const size_t bh = (size_t)b * H + hh;
  const bf16* qp = q + bh * NQ * DH;
  const bf16* kp = k + bh * NK * DH;
  const bf16* vp = vt + bh * DH * NK;
  // bias: row = q (ln-indexed), k-cols contiguous -> float4 fragments
  const float* bp0 = bias + ((size_t)b * NQ + q0 + w * 32 + ln) * NK + k0 + quad * 4;
  const float* bp1 = bp0 + (size_t)16 * NK;

  bf16x8 qf[2][2];
#pragma unroll
  for (int s = 0; s < 2; s++)
#pragma unroll
    for (int kc = 0; kc < 2; kc++)
      qf[s][kc] = *(const bf16x8*)(qp + (size_t)(q0 + w * 32 + s * 16 + ln) * DH + kc * 32 + quad * 8);

  floatx4 o[2][4] = {};
  floatx4 lac[2] = {};
  const bf16x8 ones = {(bf16)1.f, (bf16)1.f, (bf16)1.f, (bf16)1.f,
                       (bf16)1.f, (bf16)1.f, (bf16)1.f, (bf16)1.f};
  constexpr float L2E = 1.44269504f;
  constexpr float OFF = 34.6246810f;  // 24 * log2(e); scores+bias << 24 always

// one 64-row chunk: QK^T(+bias) -> exp -> P pack via wave-private Pl -> l, PV
#define CHUNK(C, SS)                                                              \
  {                                                                               \
    _Pragma("unroll")                                                             \
    for (int j_ = 0; j_ < 4; j_++)                                                \
      _Pragma("unroll")                                                           \
      for (int kc_ = 0; kc_ < 2; kc_++) {                                         \
        const int kr_ = (C) * 64 + j_ * 16 + ln;                                  \
        bf16x8 kf = *(const bf16x8*)&KL[kr_ * 64 + (((kc_ * 4 + quad) ^ (kr_ & 7)) * 8)]; \
        SS[0][j_] = __builtin_amdgcn_mfma_f32_16x16x32_bf16(kf, qf[0][kc_], SS[0][j_], 0, 0, 0); \
        SS[1][j_] = __builtin_amdgcn_mfma_f32_16x16x32_bf16(kf, qf[1][kc_], SS[1][j_], 0, 0, 0); \
      }                                                                           \
    _Pragma("unroll")                                                             \
    for (int s_ = 0; s_ < 2; s_++)                                                \
      _Pragma("unroll")                                                           \
      for (int j_ = 0; j_ < 4; j_++) {                                            \
        const float e0 = fexp2(fmaf(SS[s_][j_][0], L2E, -OFF));                   \
        const float e1 = fexp2(fmaf(SS[s_][j_][1], L2E, -OFF));                   \
        const float e2 = fexp2(fmaf(SS[s_][j_][2], L2E, -OFF));                   \
        const float e3 = fexp2(fmaf(SS[s_][j_][3], L2E, -OFF));                   \
        bf16x4 pv4 = {(bf16)e0, (bf16)e1, (bf16)e2, (bf16)e3};                    \
        const int tok_ = (j_ * 16 + quad * 4) ^ ((ln & 7) << 3);                  \
        *(bf16x4*)&Pl[w][s_][ln][tok_] = pv4;                                     \
      }                                                                           \
    asm volatile("s_waitcnt lgkmcnt(0)" ::: "memory");                            \
    bf16x8 pt[2][2];                                                              \
    _Pragma("unroll")                                                             \
    for (int s_ = 0; s_ < 2; s_++)                                                \
      _Pragma("unroll")                                                           \
      for (int kc_ = 0; kc_ < 2; kc_++) {                                         \
        const int tok_ = (kc_ * 32 + quad * 8) ^ ((ln & 7) << 3);                 \
        pt[s_][kc_] = *(const bf16x8*)&Pl[w][s_][ln][tok_];                       \
      }                                                                           \
    _Pragma("unroll")                                                             \
    for (int s_ = 0; s_ < 2; s_++)                                                \
      _Pragma("unroll")                                                           \
      for (int kc_ = 0; kc_ < 2; kc_++)                                           \
        lac[s_] = __builtin_amdgcn_mfma_f32_16x16x32_bf16(ones, pt[s_][kc_], lac[s_], 0, 0, 0); \
    _Pragma("unroll")                                                             \
    for (int jn_ = 0; jn_ < 4; jn_++)                                             \
      _Pragma("unroll")                                                           \
      for (int kc_ = 0; kc_ < 2; kc_++) {                                         \
        const int vr_ = jn_ * 16 + ln;                                            \
        bf16x8 vf = *(const bf16x8*)&VL[vr_ * 128 + (((C) * 8 + ((kc_ * 4 + quad) ^ (vr_ & 7))) * 8)]; \
        o[0][jn_] = __builtin_amdgcn_mfma_f32_16x16x32_bf16(vf, pt[0][kc_], o[0][jn_], 0, 0, 0); \
        o[1][jn_] = __builtin_amdgcn_mfma_f32_16x16x32_bf16(vf, pt[1][kc_], o[1][jn_], 0, 0, 0); \
      }                                                                           \
  }

  for (int tt = 0; tt < KTILES2; tt++) {
    const int nk0 = k0 + tt * 128;
    // ---- stage 128-deep K,V via DMA (256 threads x 4 issues each) ----
#pragma unroll
    for (int s = 0; s < 4; s++) {
      const int i = s * 256 + tid;
      const int srk = i >> 3, sck = (i & 7) ^ (srk & 7);        // K: 128 rows x 8 granules
      gload16(kp + (size_t)(nk0 + srk) * DH + sck * 8, &KL[i * 8]);
      const int srv = i >> 4, scv = (i & 15) ^ (srv & 7);       // V^T: 64 rows x 16 granules
      gload16(vp + (size_t)srv * NK + nk0 + scv * 8, &VL[i * 8]);
    }
    // ---- chunk-0 bias (C-init) issues before the barrier (overlaps drain) ----
    floatx4 s4[2][4];
#pragma unroll
    for (int j = 0; j < 4; j++) {
      s4[0][j] = *(const floatx4*)(bp0 + tt * 128 + j * 16);
      s4[1][j] = *(const floatx4*)(bp1 + tt * 128 + j * 16);
    }
    __syncthreads();
    // ---- chunk-1 bias issues here: overlaps chunk-0 compute ----
    floatx4 b1[2][4];
#pragma unroll
    for (int j = 0; j < 4; j++) {
      b1[0][j] = *(const floatx4*)(bp0 + tt * 128 + 64 + j * 16);
      b1[1][j] = *(const floatx4*)(bp1 + tt * 128 + 64 + j * 16);
    }
    CHUNK(0, s4);
    CHUNK(1, b1);
    __syncthreads();
  }
#undef CHUNK

  // ---- epilogue: O^T cols q = ln, rows d = jn*16+quad*4+r -> float4 stores --
#pragma unroll
  for (int s = 0; s < 2; s++) {
    float* op = (ks ? op1 : op0) +
                ((size_t)b * NQ + q0 + w * 32 + s * 16 + ln) * DIN + hh * 64 + quad * 4;
#pragma unroll
    for (int jn = 0; jn < 4; jn++)
      *(floatx4*)(op + jn * 16) = o[s][jn];
    if (quad == 0)
      lpart[((size_t)ks * B * H + b * H + hh) * NQ + q0 + w * 32 + s * 16 + ln] = lac[s][0];
  }
}

// ---------------- final projection fused with K-split combine ----------------
// R7 structure: 32x128 tiles, grid (4,128) = 512 blocks = 2 blocks/CU.
__global__ __launch_bounds__(256) void gemm_out(
    const float* __restrict__ op0, const float* __restrict__ op1,
    const float* __restrict__ lp, const bf16* __restrict__ W,
    float* __restrict__ outf, const float* __restrict__ bo) {
  __shared__ bf16 Al[2][32 * 32];   // 2 KB each
  __shared__ bf16 Bl[2][128 * 32];  // 8 KB each
  const int t = threadIdx.x;
  const int lane = t & 63, w = t >> 6;
  const int ln = lane & 15, quad = lane >> 4;
  const int wm = (w >> 1) * 16, wn = (w & 1) * 64;
  const int rowBase = blockIdx.y * 32;
  const int colBase = blockIdx.x * 128;

  floatx4 acc[4] = {};
  const int rA = t >> 2, oA = (t & 3) * 8;   // valid for t < 128 (32 rows x 32 cols)
  const int c0 = t, c1 = t + 256;
  const int rB0 = c0 >> 2, oB0 = (c0 & 3) * 8;
  const int rB1 = c1 >> 2, oB1 = (c1 & 3) * 8;
  const int m0 = rowBase + rA;
  const bf16* Wb = W + (size_t)colBase * DIN;

  float linv0[8];
  if (t < 128) {
#pragma unroll
    for (int h = 0; h < 8; h++) {
      const int i0 = ((m0 >> 10) * H + h) * NQ + (m0 & 1023);
      linv0[h] = 1.0f / (lp[i0] + lp[BHNQ + i0]);
    }
  }

#define STAGE_A(K0V, BUF)                                                      \
  if (t < 128) {                                                               \
    const float sA = linv0[(K0V) >> 6];                                        \
    const float* pa0 = op0 + (size_t)m0 * DIN + (K0V) + oA;                    \
    const float* pa1 = op1 + (size_t)m0 * DIN + (K0V) + oA;                    \
    float4 xa = *(const float4*)pa0, xb2 = *(const float4*)(pa0 + 4);          \
    float4 ya = *(const float4*)pa1, yb = *(const float4*)(pa1 + 4);           \
    bf16x8 v0 = {(bf16)((xa.x + ya.x) * sA), (bf16)((xa.y + ya.y) * sA),       \
                 (bf16)((xa.z + ya.z) * sA), (bf16)((xa.w + ya.w) * sA),       \
                 (bf16)((xb2.x + yb.x) * sA), (bf16)((xb2.y + yb.y) * sA),     \
                 (bf16)((xb2.z + yb.z) * sA), (bf16)((xb2.w + yb.w) * sA)};    \
    *(bf16x8*)&Al[BUF][t * 8] = v0;                                            \
  }

  STAGE_A(0, 0);
  gload16(Wb + (size_t)rB0 * DIN + oB0, &Bl[0][c0 * 8]);
  gload16(Wb + (size_t)rB1 * DIN + oB1, &Bl[0][c1 * 8]);
  __syncthreads();

#pragma unroll
  for (int kk = 0; kk < 16; kk++) {
    const int cur = kk & 1, nxt = cur ^ 1;
    if (kk < 15) {
      const int k1 = (kk + 1) * 32;
      STAGE_A(k1, nxt);
      gload16(Wb + (size_t)rB0 * DIN + k1 + oB0, &Bl[nxt][c0 * 8]);
      gload16(Wb + (size_t)rB1 * DIN + k1 + oB1, &Bl[nxt][c1 * 8]);
    }
    bf16x8 af, bfr[4];
    af = *(const bf16x8*)&Al[cur][(wm + ln) * 32 + quad * 8];
#pragma unroll
    for (int j = 0; j < 4; j++)
      bfr[j] = *(const bf16x8*)&Bl[cur][(wn + j * 16 + ln) * 32 + quad * 8];
#pragma unroll
    for (int j = 0; j < 4; j++)
      acc[j] = __builtin_amdgcn_mfma_f32_16x16x32_bf16(af, bfr[j], acc[j], 0, 0, 0);
    __syncthreads();
  }
#undef STAGE_A

#pragma unroll
  for (int j = 0; j < 4; j++)
#pragma unroll
    for (int r = 0; r < 4; r++) {
      const int m = rowBase + wm + quad * 4 + r;
      const int n = colBase + wn + j * 16 + ln;
      outf[(size_t)m * DIN + n] = acc[j][r] + bo[n];
    }
}

extern "C" void kernel_launch(void* const* d_in, const int* in_sizes, int n_in,
                              void* d_out, int out_size, void* d_ws, size_t ws_size,
                              hipStream_t stream) {
  const float* x    = (const float*)d_in[0];
  const float* ctx  = (const float*)d_in[1];
  const float* bias = (const float*)d_in[2];
  const float* Wq   = (const float*)d_in[3];
  const float* Wk   = (const float*)d_in[4];
  const float* Wv   = (const float*)d_in[5];
  const float* Wo   = (const float*)d_in[6];
  const float* bo   = (const float*)d_in[7];
  float* out = (float*)d_out;

  char* p = (char*)d_ws;
  bf16* wqb  = (bf16*)(p + 0);              // 512 KB
  bf16* wkb  = (bf16*)(p + 524288);
  bf16* wvb  = (bf16*)(p + 1048576);
  bf16* wob  = (bf16*)(p + 1572864);
  bf16* qb   = (bf16*)(p + 2097152);        // 4 MB
  bf16* kb   = (bf16*)(p + 6291456);        // 8 MB
  bf16* vtb  = (bf16*)(p + 14680064);       // 8 MB
  float* op0 = (float*)(p + 23068672);      // 8 MB
  float* op1 = (float*)(p + 31457280);      // 8 MB
  float* lpart = (float*)(p + 39845888);    // 256 KB

  cvt_w<<<1024, 256, 0, stream>>>(Wq, Wk, Wv, Wo, wqb, wkb, wvb, wob);
  gemm_qkv<<<dim3(4, 128, 2), 256, 0, stream>>>(x, ctx, wqb, wkb, wvb, qb, kb, vtb);
  attn_fwd<<<dim3(NQ / 128, H, B * KSPLIT), 256, 0, stream>>>(qb, kb, vtb, bias, op0, op1, lpart);
  gemm_out<<<dim3(4, 128), 256, 0, stream>>>(op0, op1, lpart, wob, out, bo);
}